// Round 6
// baseline (312.818 us; speedup 1.0000x reference)
//
#include <hip/hip_runtime.h>
#include <hip/hip_bf16.h>

#define N_NODES 20000
#define N_EDGES 32768
#define DIM 128
#define N_REL 474
#define N_BASIS 64
#define TILE_E 64
#define MAXCH (N_EDGES / TILE_E + N_REL)   // 986 upper bound on chunk count
#define WSTRIDE 260                         // LDS row stride (shorts) for wmix staging

typedef __bf16 bf16x8 __attribute__((ext_vector_type(8)));
typedef float f32x4 __attribute__((ext_vector_type(4)));

// ---------- helpers ----------
__device__ __forceinline__ unsigned short f2b(float f) {   // RNE fp32 -> bf16 bits
    unsigned u = __float_as_uint(f);
    unsigned r = (u + 0x7FFFu + ((u >> 16) & 1u)) >> 16;
    return (unsigned short)r;
}
__device__ __forceinline__ float b2f(unsigned short s) {
    return __uint_as_float(((unsigned)s) << 16);
}
__device__ __forceinline__ __bf16 u2b(unsigned short u) {
    union { unsigned short u; __bf16 b; } c; c.u = u; return c.b;
}

// ---------- xb = bf16(emb[entity]) ----------
__global__ void gather_kernel(const float4* __restrict__ emb, const int* __restrict__ entity,
                              ushort4* __restrict__ xb, int total4) {
    int i = blockIdx.x * blockDim.x + threadIdx.x;
    if (i >= total4) return;
    int n = i >> 5;       // 32 float4 per node
    int rem = i & 31;
    float4 v = emb[(size_t)entity[n] * 32 + rem];
    ushort4 s;
    s.x = f2b(v.x); s.y = f2b(v.y); s.z = f2b(v.z); s.w = f2b(v.w);
    xb[i] = s;
}

// ---------- count by relation AND by dst ----------
__global__ void count2_kernel(const int* __restrict__ et, const int* __restrict__ dst,
                              int* __restrict__ cntR, int* __restrict__ cntD, int E) {
    int e = blockIdx.x * blockDim.x + threadIdx.x;
    if (e < E) {
        atomicAdd(&cntR[et[e]], 1);
        atomicAdd(&cntD[dst[e]], 1);
    }
}

// ---------- single-block scan over R=474 ----------
__global__ void scanr_kernel(const int* __restrict__ cnt, int* __restrict__ offs,
                             int* __restrict__ cursor, int R, int E) {
    __shared__ int s[512];
    int t = threadIdx.x;
    int v = (t < R) ? cnt[t] : 0;
    s[t] = v;
    __syncthreads();
    for (int d = 1; d < 512; d <<= 1) {
        int add = (t >= d) ? s[t - d] : 0;
        __syncthreads();
        s[t] += add;
        __syncthreads();
    }
    if (t < R) { int excl = s[t] - v; offs[t] = excl; cursor[t] = excl; }
    if (t == 0) offs[R] = E;
}

// ---------- single-block scan over N=20000 (1024 thr x 20 elems) ----------
__global__ __launch_bounds__(1024) void scand_kernel(const int* __restrict__ cnt,
                                                     int* __restrict__ offs,
                                                     int* __restrict__ cursor, int N, int E) {
    __shared__ int s[1024];
    int t = threadIdx.x;
    const int PER = 20;
    int base = t * PER;
    int vals[PER];
    int sum = 0;
#pragma unroll
    for (int i = 0; i < PER; i++) {
        int idx = base + i;
        int v = (idx < N) ? cnt[idx] : 0;
        vals[i] = v; sum += v;
    }
    s[t] = sum;
    __syncthreads();
    for (int d = 1; d < 1024; d <<= 1) {
        int add = (t >= d) ? s[t - d] : 0;
        __syncthreads();
        s[t] += add;
        __syncthreads();
    }
    int excl = s[t] - sum;
#pragma unroll
    for (int i = 0; i < PER; i++) {
        int idx = base + i;
        if (idx < N) { offs[idx] = excl; cursor[idx] = excl; excl += vals[i]; }
    }
    if (t == 1023) offs[N] = E;
}

// ---------- scatter into both CSRs ----------
__global__ void scatter2_kernel(const int* __restrict__ et, const int* __restrict__ dst,
                                int* __restrict__ curR, int* __restrict__ curD,
                                int* __restrict__ eidsR, int* __restrict__ eidsD, int E) {
    int e = blockIdx.x * blockDim.x + threadIdx.x;
    if (e < E) {
        int p = atomicAdd(&curR[et[e]], 1);
        eidsR[p] = e;
        int q = atomicAdd(&curD[dst[e]], 1);
        eidsD[q] = e;
    }
}

// ---------- build (relation, 64-edge-chunk) work list ----------
__global__ void chunkbuild_kernel(const int* __restrict__ offs, int* __restrict__ chunk_r,
                                  int* __restrict__ chunk_off, int* __restrict__ nchunks, int R) {
    int r = blockIdx.x * blockDim.x + threadIdx.x;
    if (r >= R) return;
    int s = offs[r], e = offs[r + 1];
    int nc = (e - s + TILE_E - 1) / TILE_E;
    if (nc > 0) {
        int b = atomicAdd(nchunks, nc);
        for (int c = 0; c < nc; c++) { chunk_r[b + c] = r; chunk_off[b + c] = s + c * TILE_E; }
    }
}

// ---------- fused attention softmax: one wave per dst node, no atomics ----------
__global__ __launch_bounds__(256) void attn_kernel(const unsigned short* __restrict__ xb,
                                                   const float* __restrict__ w,
                                                   const int* __restrict__ src,
                                                   const int* __restrict__ et,
                                                   const int* __restrict__ offsD,
                                                   const int* __restrict__ eidsD,
                                                   float* __restrict__ alpha, int N) {
    int node = (blockIdx.x * 256 + threadIdx.x) >> 6;
    int lane = threadIdx.x & 63;
    if (node >= N) return;
    int s0 = offsD[node], s1 = offsD[node + 1];
    int k = s1 - s0;
    if (k <= 0) return;
    unsigned dx = ((const unsigned*)(xb + (size_t)node * DIM))[lane];
    float dx0 = b2f((unsigned short)(dx & 0xFFFF)), dx1 = b2f((unsigned short)(dx >> 16));

    auto edge_logit = [&](int j) -> float {
        int e = eidsD[s0 + j];
        int sN = src[e], r = et[e];
        unsigned sx = ((const unsigned*)(xb + (size_t)sN * DIM))[lane];
        float2 wv = ((const float2*)(w + (size_t)r * DIM))[lane];
        float v = b2f((unsigned short)(sx & 0xFFFF)) * wv.x * dx0
                + b2f((unsigned short)(sx >> 16)) * wv.y * dx1;
        for (int o = 32; o > 0; o >>= 1) v += __shfl_xor(v, o, 64);
        return v;   // identical on all lanes
    };

    if (k <= 64) {
        float stash = 0.f, m = -1e30f;
        for (int j = 0; j < k; j++) {
            float v = edge_logit(j);
            if (lane == j) stash = v;
            m = fmaxf(m, v);
        }
        float a = (lane < k) ? expf(stash - m) : 0.f;
        float den = a;
        for (int o = 32; o > 0; o >>= 1) den += __shfl_xor(den, o, 64);
        if (lane < k) alpha[eidsD[s0 + lane]] = a / den;
    } else {
        float m = -1e30f;
        for (int j = 0; j < k; j++) m = fmaxf(m, edge_logit(j));
        float den = 0.f;
        for (int j = 0; j < k; j++) den += expf(edge_logit(j) - m);
        for (int j = 0; j < k; j++) {
            float v = edge_logit(j);
            if (lane == 0) alpha[eidsD[s0 + j]] = expf(v - m) / den;
        }
    }
}

// ---------- W = att @ basis via MFMA: [R,64] @ [64, D*D] -> bf16 ----------
__global__ __launch_bounds__(256) void wmix_kernel(const float* __restrict__ att,
                                                   const float* __restrict__ basis,
                                                   unsigned short* __restrict__ W, int R) {
    int io0 = blockIdx.x * 256;
    int r0 = blockIdx.y * 16;
    __shared__ unsigned short bt[64 * WSTRIDE];
    int t = threadIdx.x;
#pragma unroll
    for (int p = 0; p < 16; p++) {
        int c = t + 256 * p;
        int k = c >> 6, of = c & 63;
        float4 v = *(const float4*)(basis + (size_t)k * (DIM * DIM) + io0 + of * 4);
        ushort4 s;
        s.x = f2b(v.x); s.y = f2b(v.y); s.z = f2b(v.z); s.w = f2b(v.w);
        *(ushort4*)&bt[k * WSTRIDE + of * 4] = s;
    }
    __syncthreads();

    int w = t >> 6, l = t & 63, n = l & 15, q = l >> 4;
    int rm = min(r0 + n, R - 1);
    f32x4 acc[4] = {};
#pragma unroll
    for (int kb = 0; kb < 2; kb++) {
        int kbase = kb * 32 + q * 8;
        const float* ap = att + (size_t)rm * N_BASIS + kbase;
        bf16x8 a;
#pragma unroll
        for (int j = 0; j < 8; j++) a[j] = u2b(f2b(ap[j]));
#pragma unroll
        for (int c = 0; c < 4; c++) {
            int ob = w * 64 + c * 16 + n;
            bf16x8 b;
#pragma unroll
            for (int j = 0; j < 8; j++) b[j] = u2b(bt[(kbase + j) * WSTRIDE + ob]);
            acc[c] = __builtin_amdgcn_mfma_f32_16x16x32_bf16(a, b, acc[c], 0, 0, 0);
        }
    }
#pragma unroll
    for (int c = 0; c < 4; c++) {
        int col = io0 + w * 64 + c * 16 + n;
#pragma unroll
        for (int rg = 0; rg < 4; rg++) {
            int r = r0 + q * 4 + rg;
            if (r < R) W[(size_t)r * (DIM * DIM) + col] = f2b(acc[c][rg]);
        }
    }
}

// ---------- msg: per 64-edge chunk, (64x128)@(128x128) via MFMA -> msgbuf bf16 ----------
__global__ __launch_bounds__(256) void msg_kernel(const unsigned short* __restrict__ xb,
                                                  const unsigned short* __restrict__ W,
                                                  const int* __restrict__ chunk_r,
                                                  const int* __restrict__ chunk_off,
                                                  const int* __restrict__ nchunks,
                                                  const int* __restrict__ eidsR,
                                                  const int* __restrict__ offsR,
                                                  const int* __restrict__ src,
                                                  unsigned short* __restrict__ msgb) {
    if ((int)blockIdx.x >= *nchunks) return;
    int r = chunk_r[blockIdx.x];
    int base = chunk_off[blockIdx.x];
    int nE = min(TILE_E, offsR[r + 1] - base);
    const unsigned short* Wr = W + (size_t)r * (DIM * DIM);

    __shared__ unsigned short wt[128 * 136];   // [k][o] pad
    __shared__ unsigned short xjf[8192];       // A-frag order, 64 edges
    __shared__ int sed[TILE_E];

    int t = threadIdx.x;
    if (t < TILE_E) sed[t] = (t < nE) ? eidsR[base + t] : 0;
    // stage A: slot c = (rt*4+kb)*64 + q*16 + m; consecutive lanes -> consecutive slots
#pragma unroll
    for (int p = 0; p < 4; p++) {
        int c = t + 256 * p;
        int g = c >> 6;                 // rt*4+kb
        int rt = g >> 2, kb = g & 3;
        int q = (c >> 4) & 3, m = c & 15;
        int e = rt * 16 + m;
        int oct = kb * 4 + q;
        int4 v = make_int4(0, 0, 0, 0);
        if (e < nE)
            v = *(const int4*)(xb + (size_t)src[eidsR[base + e]] * DIM + oct * 8);
        *(int4*)&xjf[c * 8] = v;
    }
    // stage W tile: 128 rows x 16 octets = 2048 int4 chunks
#pragma unroll
    for (int p = 0; p < 8; p++) {
        int c = t + 256 * p;
        int k = c >> 4, oct = c & 15;
        int4 v = *(const int4*)(Wr + k * DIM + oct * 8);
        *(int4*)&wt[k * 136 + oct * 8] = v;
    }
    __syncthreads();

    int w = t >> 6, l = t & 63, n = l & 15, q = l >> 4;
    f32x4 acc[2][4] = {};                       // [ct-local][rt]
#pragma unroll
    for (int kb = 0; kb < 4; kb++) {
        bf16x8 a[4];
#pragma unroll
        for (int rt = 0; rt < 4; rt++) a[rt] = *(const bf16x8*)&xjf[((rt * 4 + kb) * 64 + l) * 8];
        int kbase = kb * 32 + q * 8;
#pragma unroll
        for (int c = 0; c < 2; c++) {
            int ob = (w * 2 + c) * 16 + n;
            bf16x8 b;
#pragma unroll
            for (int j = 0; j < 8; j++) b[j] = u2b(wt[(kbase + j) * 136 + ob]);
#pragma unroll
            for (int rt = 0; rt < 4; rt++)
                acc[c][rt] = __builtin_amdgcn_mfma_f32_16x16x32_bf16(a[rt], b, acc[c][rt], 0, 0, 0);
        }
    }
#pragma unroll
    for (int c = 0; c < 2; c++) {
        int col = (w * 2 + c) * 16 + n;
#pragma unroll
        for (int rt = 0; rt < 4; rt++) {
#pragma unroll
            for (int rg = 0; rg < 4; rg++) {
                int e = rt * 16 + q * 4 + rg;
                if (e < nE)
                    msgb[(size_t)sed[e] * DIM + col] = f2b(acc[c][rt][rg]);
            }
        }
    }
}

// ---------- fused: out = sum_in alpha*msg + x @ root + bias; mode 1 = relu+bf16 ----------
__global__ __launch_bounds__(256) void reduce_root_kernel(const unsigned short* __restrict__ xb,
                                                          const float* __restrict__ rootM,
                                                          const float* __restrict__ bias,
                                                          const int* __restrict__ offsD,
                                                          const int* __restrict__ eidsD,
                                                          const float* __restrict__ alpha,
                                                          const unsigned short* __restrict__ msgb,
                                                          unsigned short* __restrict__ outb,
                                                          float* __restrict__ outf,
                                                          int mode, int N) {
    int n0 = blockIdx.x * 64;
    __shared__ unsigned short wt[128 * 136];   // root bf16 [k][o] pad
    __shared__ unsigned short xrf[8192];       // 64 rows A-frag order
    int t = threadIdx.x;
    // stage x rows (slot-ordered like msg)
#pragma unroll
    for (int p = 0; p < 4; p++) {
        int c = t + 256 * p;
        int g = c >> 6;
        int rt = g >> 2, kb = g & 3;
        int q = (c >> 4) & 3, m = c & 15;
        int row = n0 + rt * 16 + m;
        int oct = kb * 4 + q;
        int4 v = make_int4(0, 0, 0, 0);
        if (row < N) v = *(const int4*)(xb + (size_t)row * DIM + oct * 8);
        *(int4*)&xrf[c * 8] = v;
    }
    // stage root fp32 -> bf16: 4096 float4 chunks
#pragma unroll
    for (int p = 0; p < 16; p++) {
        int c = t + 256 * p;
        int k = c >> 5, of = c & 31;
        float4 v = *(const float4*)(rootM + k * DIM + of * 4);
        ushort4 s;
        s.x = f2b(v.x); s.y = f2b(v.y); s.z = f2b(v.z); s.w = f2b(v.w);
        *(ushort4*)&wt[k * 136 + of * 4] = s;
    }
    __syncthreads();

    int w = t >> 6, l = t & 63, n = l & 15, q = l >> 4;
    f32x4 acc[2][4] = {};
#pragma unroll
    for (int kb = 0; kb < 4; kb++) {
        bf16x8 a[4];
#pragma unroll
        for (int rt = 0; rt < 4; rt++) a[rt] = *(const bf16x8*)&xrf[((rt * 4 + kb) * 64 + l) * 8];
        int kbase = kb * 32 + q * 8;
#pragma unroll
        for (int c = 0; c < 2; c++) {
            int ob = (w * 2 + c) * 16 + n;
            bf16x8 b;
#pragma unroll
            for (int j = 0; j < 8; j++) b[j] = u2b(wt[(kbase + j) * 136 + ob]);
#pragma unroll
            for (int rt = 0; rt < 4; rt++)
                acc[c][rt] = __builtin_amdgcn_mfma_f32_16x16x32_bf16(a[rt], b, acc[c][rt], 0, 0, 0);
        }
    }
    int col0 = (w * 2 + 0) * 16 + n;
    int col1 = (w * 2 + 1) * 16 + n;
    float b0 = bias[col0], b1 = bias[col1];
#pragma unroll
    for (int rt = 0; rt < 4; rt++) {
#pragma unroll
        for (int rg = 0; rg < 4; rg++) {
            int row = n0 + rt * 16 + q * 4 + rg;
            if (row >= N) continue;
            float v0 = acc[0][rt][rg] + b0;
            float v1 = acc[1][rt][rg] + b1;
            int j0 = offsD[row], j1 = offsD[row + 1];
            for (int j = j0; j < j1; j++) {
                int e = eidsD[j];
                float al = alpha[e];
                const unsigned short* mr = msgb + (size_t)e * DIM;
                v0 += al * b2f(mr[col0]);
                v1 += al * b2f(mr[col1]);
            }
            if (mode) {
                outb[(size_t)row * DIM + col0] = f2b(fmaxf(v0, 0.f));
                outb[(size_t)row * DIM + col1] = f2b(fmaxf(v1, 0.f));
            } else {
                outf[(size_t)row * DIM + col0] = v0;
                outf[(size_t)row * DIM + col1] = v1;
            }
        }
    }
}

extern "C" void kernel_launch(void* const* d_in, const int* in_sizes, int n_in,
                              void* d_out, int out_size, void* d_ws, size_t ws_size,
                              hipStream_t stream) {
    const int N = N_NODES, E = N_EDGES, R = N_REL;

    const int* entity = (const int*)d_in[0];
    const int* eidx   = (const int*)d_in[1];
    const int* src    = eidx;
    const int* dst    = eidx + E;
    const int* etype  = (const int*)d_in[2];
    const float* emb  = (const float*)d_in[3];
    const float* basis1 = (const float*)d_in[4];
    const float* att1   = (const float*)d_in[5];
    const float* w1     = (const float*)d_in[6];
    const float* root1  = (const float*)d_in[7];
    const float* bias1  = (const float*)d_in[8];
    const float* basis2 = (const float*)d_in[9];
    const float* att2   = (const float*)d_in[10];
    const float* w2     = (const float*)d_in[11];
    const float* root2  = (const float*)d_in[12];
    const float* bias2  = (const float*)d_in[13];
    float* out = (float*)d_out;

    size_t off = 0;
    auto alloc = [&](size_t bytes) -> void* {
        void* p = (char*)d_ws + off;
        off += (bytes + 255) & ~(size_t)255;
        return p;
    };
    unsigned short* W    = (unsigned short*)alloc((size_t)R * DIM * DIM * 2);
    unsigned short* xb   = (unsigned short*)alloc((size_t)N * DIM * 2);
    unsigned short* hb   = (unsigned short*)alloc((size_t)N * DIM * 2);
    unsigned short* msgb = (unsigned short*)alloc((size_t)E * DIM * 2);
    float* alpha  = (float*)alloc((size_t)E * 4);
    // zeroed meta region: cntR | nchunks | cntD
    int* meta     = (int*)alloc((size_t)(R + 1 + N) * 4);
    int* cntR     = meta;
    int* nchunks  = meta + R;
    int* cntD     = meta + R + 1;
    int* offsR    = (int*)alloc((size_t)(R + 1) * 4);
    int* curR     = (int*)alloc((size_t)R * 4);
    int* eidsR    = (int*)alloc((size_t)E * 4);
    int* offsD    = (int*)alloc((size_t)(N + 1) * 4);
    int* curD     = (int*)alloc((size_t)N * 4);
    int* eidsD    = (int*)alloc((size_t)E * 4);
    int* chunk_r  = (int*)alloc((size_t)MAXCH * 4);
    int* chunk_o  = (int*)alloc((size_t)MAXCH * 4);

    // ---- prep ----
    hipMemsetAsync(meta, 0, (size_t)(R + 1 + N) * 4, stream);
    {
        int total4 = N * DIM / 4;
        gather_kernel<<<(total4 + 255) / 256, 256, 0, stream>>>(
            (const float4*)emb, entity, (ushort4*)xb, total4);
    }
    count2_kernel<<<(E + 255) / 256, 256, 0, stream>>>(etype, dst, cntR, cntD, E);
    scanr_kernel<<<1, 512, 0, stream>>>(cntR, offsR, curR, R, E);
    scand_kernel<<<1, 1024, 0, stream>>>(cntD, offsD, curD, N, E);
    scatter2_kernel<<<(E + 255) / 256, 256, 0, stream>>>(etype, dst, curR, curD, eidsR, eidsD, E);
    chunkbuild_kernel<<<(R + 255) / 256, 256, 0, stream>>>(offsR, chunk_r, chunk_o, nchunks, R);

    // ---- layer 1: xb -> hb (relu, bf16) ----
    attn_kernel<<<N / 4, 256, 0, stream>>>(xb, w1, src, etype, offsD, eidsD, alpha, N);
    wmix_kernel<<<dim3(64, 30), 256, 0, stream>>>(att1, basis1, W, R);
    msg_kernel<<<MAXCH, 256, 0, stream>>>(xb, W, chunk_r, chunk_o, nchunks, eidsR, offsR, src, msgb);
    reduce_root_kernel<<<(N + 63) / 64, 256, 0, stream>>>(xb, root1, bias1, offsD, eidsD,
                                                          alpha, msgb, hb, nullptr, 1, N);

    // ---- layer 2: hb -> out (fp32) ----
    attn_kernel<<<N / 4, 256, 0, stream>>>(hb, w2, src, etype, offsD, eidsD, alpha, N);
    wmix_kernel<<<dim3(64, 30), 256, 0, stream>>>(att2, basis2, W, R);
    msg_kernel<<<MAXCH, 256, 0, stream>>>(hb, W, chunk_r, chunk_o, nchunks, eidsR, offsR, src, msgb);
    reduce_root_kernel<<<(N + 63) / 64, 256, 0, stream>>>(hb, root2, bias2, offsD, eidsD,
                                                          alpha, msgb, nullptr, out, 0, N);
}

// Round 7
// 265.287 us; speedup vs baseline: 1.1792x; 1.1792x over previous
//
#include <hip/hip_runtime.h>
#include <hip/hip_bf16.h>

#define N_NODES 20000
#define N_EDGES 32768
#define DIM 128
#define N_REL 474
#define N_BASIS 64
#define TILE_E 64
#define MAXCH (N_EDGES / TILE_E + N_REL)   // 986 upper bound on chunk count
#define WSTRIDE 260                         // LDS row stride (shorts) for wmix staging

typedef __bf16 bf16x8 __attribute__((ext_vector_type(8)));
typedef float f32x4 __attribute__((ext_vector_type(4)));

// ---------- helpers ----------
__device__ __forceinline__ unsigned ordf(float f) {
    unsigned u = __float_as_uint(f);
    return (u & 0x80000000u) ? ~u : (u | 0x80000000u);
}
__device__ __forceinline__ float unordf(unsigned u) {
    unsigned v = (u & 0x80000000u) ? (u & 0x7FFFFFFFu) : ~u;
    return __uint_as_float(v);
}
__device__ __forceinline__ unsigned short f2b(float f) {   // RNE fp32 -> bf16 bits
    unsigned u = __float_as_uint(f);
    unsigned r = (u + 0x7FFFu + ((u >> 16) & 1u)) >> 16;
    return (unsigned short)r;
}
__device__ __forceinline__ float b2f(unsigned short s) {
    return __uint_as_float(((unsigned)s) << 16);
}
__device__ __forceinline__ __bf16 u2b(unsigned short u) {
    union { unsigned short u; __bf16 b; } c; c.u = u; return c.b;
}

// ---------- xb = bf16(emb[entity]) ----------
__global__ void gather_kernel(const float4* __restrict__ emb, const int* __restrict__ entity,
                              ushort4* __restrict__ xb, int total4) {
    int i = blockIdx.x * blockDim.x + threadIdx.x;
    if (i >= total4) return;
    int n = i >> 5;       // 32 float4 per node
    int rem = i & 31;
    float4 v = emb[(size_t)entity[n] * 32 + rem];
    ushort4 s;
    s.x = f2b(v.x); s.y = f2b(v.y); s.z = f2b(v.z); s.w = f2b(v.w);
    xb[i] = s;
}

// ---------- edge grouping by relation ----------
__global__ void count_kernel(const int* __restrict__ et, int* __restrict__ cnt, int E) {
    int e = blockIdx.x * blockDim.x + threadIdx.x;
    if (e < E) atomicAdd(&cnt[et[e]], 1);
}

// scan over R + emit (relation, 64-edge-chunk) work list in one launch
__global__ void scanr_kernel(const int* __restrict__ cnt, int* __restrict__ offs,
                             int* __restrict__ cursor, int* __restrict__ chunk_r,
                             int* __restrict__ chunk_o, int* __restrict__ nchunks,
                             int R, int E) {
    __shared__ int s[512];
    int t = threadIdx.x;
    int v = (t < R) ? cnt[t] : 0;
    s[t] = v;
    __syncthreads();
    for (int d = 1; d < 512; d <<= 1) {
        int add = (t >= d) ? s[t - d] : 0;
        __syncthreads();
        s[t] += add;
        __syncthreads();
    }
    int excl = s[t] - v;
    if (t < R) { offs[t] = excl; cursor[t] = excl; }
    if (t == 0) offs[R] = E;
    int nc = (v + TILE_E - 1) / TILE_E;
    if (t < R && nc > 0) {
        int b = atomicAdd(nchunks, nc);
        for (int c = 0; c < nc; c++) { chunk_r[b + c] = t; chunk_o[b + c] = excl + c * TILE_E; }
    }
}

__global__ void scatter_kernel(const int* __restrict__ et, int* __restrict__ cursor,
                               int* __restrict__ eids, int E) {
    int e = blockIdx.x * blockDim.x + threadIdx.x;
    if (e < E) {
        int p = atomicAdd(&cursor[et[e]], 1);
        eids[p] = e;
    }
}

// ---------- per-edge attention logit + segment max (bf16 x, fp32 w) ----------
__global__ __launch_bounds__(256) void logit_kernel(const unsigned short* __restrict__ xb,
                                                    const float* __restrict__ w,
                                                    const int* __restrict__ src,
                                                    const int* __restrict__ dst,
                                                    const int* __restrict__ et,
                                                    float* __restrict__ alpha,
                                                    unsigned* __restrict__ nmax, int E) {
    int wid = (blockIdx.x * 256 + threadIdx.x) >> 6;
    int lane = threadIdx.x & 63;
    if (wid >= E) return;
    int s = src[wid], d = dst[wid], r = et[wid];
    unsigned ax = ((const unsigned*)(xb + (size_t)s * DIM))[lane];
    unsigned bx = ((const unsigned*)(xb + (size_t)d * DIM))[lane];
    float2 wv = ((const float2*)(w + (size_t)r * DIM))[lane];
    float v = b2f((unsigned short)(ax & 0xFFFF)) * wv.x * b2f((unsigned short)(bx & 0xFFFF))
            + b2f((unsigned short)(ax >> 16)) * wv.y * b2f((unsigned short)(bx >> 16));
    for (int off = 32; off > 0; off >>= 1) v += __shfl_xor(v, off, 64);
    if (lane == 0) {
        alpha[wid] = v;
        atomicMax(&nmax[d], ordf(v));
    }
}

// ---------- exp(alpha - max) + segment denom ----------
__global__ void expden_kernel(float* __restrict__ alpha, const int* __restrict__ dst,
                              const unsigned* __restrict__ nmax, float* __restrict__ denom, int E) {
    int e = blockIdx.x * blockDim.x + threadIdx.x;
    if (e >= E) return;
    int d = dst[e];
    float m = unordf(nmax[d]);
    float a = expf(alpha[e] - m);
    alpha[e] = a;
    atomicAdd(&denom[d], a);
}

// ---------- W = att @ basis via MFMA: [R,64] @ [64, D*D] -> bf16 ----------
// grid (64 io-chunks of 256, 8 r-tiles of 64); basis chunk staged once per block.
__global__ __launch_bounds__(256) void wmix_kernel(const float* __restrict__ att,
                                                   const float* __restrict__ basis,
                                                   unsigned short* __restrict__ W, int R) {
    int io0 = blockIdx.x * 256;
    int r0 = blockIdx.y * 64;
    __shared__ unsigned short bt[64 * WSTRIDE];
    int t = threadIdx.x;
#pragma unroll
    for (int p = 0; p < 16; p++) {
        int c = t + 256 * p;
        int k = c >> 6, of = c & 63;
        float4 v = *(const float4*)(basis + (size_t)k * (DIM * DIM) + io0 + of * 4);
        ushort4 s;
        s.x = f2b(v.x); s.y = f2b(v.y); s.z = f2b(v.z); s.w = f2b(v.w);
        *(ushort4*)&bt[k * WSTRIDE + of * 4] = s;
    }
    __syncthreads();

    int w = t >> 6, l = t & 63, n = l & 15, q = l >> 4;
    f32x4 acc[4][4] = {};                       // [rt][c]
#pragma unroll
    for (int kb = 0; kb < 2; kb++) {
        int kbase = kb * 32 + q * 8;
        bf16x8 a[4];
#pragma unroll
        for (int rt = 0; rt < 4; rt++) {
            int rm = min(r0 + rt * 16 + n, R - 1);
            const float* ap = att + (size_t)rm * N_BASIS + kbase;
#pragma unroll
            for (int j = 0; j < 8; j++) a[rt][j] = u2b(f2b(ap[j]));
        }
#pragma unroll
        for (int c = 0; c < 4; c++) {
            int ob = w * 64 + c * 16 + n;
            bf16x8 b;
#pragma unroll
            for (int j = 0; j < 8; j++) b[j] = u2b(bt[(kbase + j) * WSTRIDE + ob]);
#pragma unroll
            for (int rt = 0; rt < 4; rt++)
                acc[rt][c] = __builtin_amdgcn_mfma_f32_16x16x32_bf16(a[rt], b, acc[rt][c], 0, 0, 0);
        }
    }
#pragma unroll
    for (int rt = 0; rt < 4; rt++) {
#pragma unroll
        for (int c = 0; c < 4; c++) {
            int col = io0 + w * 64 + c * 16 + n;
#pragma unroll
            for (int rg = 0; rg < 4; rg++) {
                int r = r0 + rt * 16 + q * 4 + rg;
                if (r < R) W[(size_t)r * (DIM * DIM) + col] = f2b(acc[rt][c][rg]);
            }
        }
    }
}

// ---------- msg: per 64-edge chunk, (64x128)@(128x128) MFMA + alpha-scaled atomicAdd ----------
__global__ __launch_bounds__(256) void msg_kernel(const unsigned short* __restrict__ xb,
                                                  const unsigned short* __restrict__ W,
                                                  const int* __restrict__ chunk_r,
                                                  const int* __restrict__ chunk_off,
                                                  const int* __restrict__ nchunks,
                                                  const int* __restrict__ eids,
                                                  const int* __restrict__ offs,
                                                  const int* __restrict__ src,
                                                  const int* __restrict__ dst,
                                                  const float* __restrict__ ae,
                                                  const float* __restrict__ denom,
                                                  float* __restrict__ outacc) {
    if ((int)blockIdx.x >= *nchunks) return;
    int r = chunk_r[blockIdx.x];
    int base = chunk_off[blockIdx.x];
    int nE = min(TILE_E, offs[r + 1] - base);
    const unsigned short* Wr = W + (size_t)r * (DIM * DIM);

    __shared__ unsigned short wt[128 * 136];   // [k][o] pad
    __shared__ unsigned short xjf[8192];       // A-frag order, 64 edges
    __shared__ float scf[TILE_E];
    __shared__ int sdd[TILE_E];

    int t = threadIdx.x;
    if (t < TILE_E) {
        if (t < nE) {
            int e = eids[base + t];
            int d_ = dst[e];
            sdd[t] = d_;
            scf[t] = ae[e] / denom[d_];
        } else { sdd[t] = 0; scf[t] = 0.f; }
    }
    // stage A: slot c = (rt*4+kb)*64 + q*16 + m; consecutive lanes -> consecutive slots
#pragma unroll
    for (int p = 0; p < 4; p++) {
        int c = t + 256 * p;
        int g = c >> 6;                 // rt*4+kb
        int rt = g >> 2, kb = g & 3;
        int q = (c >> 4) & 3, m = c & 15;
        int e = rt * 16 + m;
        int oct = kb * 4 + q;
        int4 v = make_int4(0, 0, 0, 0);
        if (e < nE)
            v = *(const int4*)(xb + (size_t)src[eids[base + e]] * DIM + oct * 8);
        *(int4*)&xjf[c * 8] = v;
    }
    // stage W tile: 128 rows x 16 octets = 2048 int4 chunks
#pragma unroll
    for (int p = 0; p < 8; p++) {
        int c = t + 256 * p;
        int k = c >> 4, oct = c & 15;
        int4 v = *(const int4*)(Wr + k * DIM + oct * 8);
        *(int4*)&wt[k * 136 + oct * 8] = v;
    }
    __syncthreads();

    int w = t >> 6, l = t & 63, n = l & 15, q = l >> 4;
    f32x4 acc[2][4] = {};                       // [ct-local][rt]
#pragma unroll
    for (int kb = 0; kb < 4; kb++) {
        bf16x8 a[4];
#pragma unroll
        for (int rt = 0; rt < 4; rt++) a[rt] = *(const bf16x8*)&xjf[((rt * 4 + kb) * 64 + l) * 8];
        int kbase = kb * 32 + q * 8;
#pragma unroll
        for (int c = 0; c < 2; c++) {
            int ob = (w * 2 + c) * 16 + n;
            bf16x8 b;
#pragma unroll
            for (int j = 0; j < 8; j++) b[j] = u2b(wt[(kbase + j) * 136 + ob]);
#pragma unroll
            for (int rt = 0; rt < 4; rt++)
                acc[c][rt] = __builtin_amdgcn_mfma_f32_16x16x32_bf16(a[rt], b, acc[c][rt], 0, 0, 0);
        }
    }
#pragma unroll
    for (int c = 0; c < 2; c++) {
        int col = (w * 2 + c) * 16 + n;
#pragma unroll
        for (int rt = 0; rt < 4; rt++) {
#pragma unroll
            for (int rg = 0; rg < 4; rg++) {
                int e = rt * 16 + q * 4 + rg;
                if (e < nE)
                    atomicAdd(&outacc[(size_t)sdd[e] * DIM + col], scf[e] * acc[c][rt][rg]);
            }
        }
    }
}

// ---------- root: out = acc + x @ root + bias via MFMA; mode 1 = relu+bf16, 0 = fp32 ----------
__global__ __launch_bounds__(256) void root_kernel(const unsigned short* __restrict__ xb,
                                                   const float* __restrict__ rootM,
                                                   const float* __restrict__ bias,
                                                   const float* __restrict__ accbuf,
                                                   unsigned short* __restrict__ outb,
                                                   float* __restrict__ outf,
                                                   int mode, int N) {
    int n0 = blockIdx.x * 64;
    __shared__ unsigned short wt[128 * 136];   // root bf16 [k][o] pad
    __shared__ unsigned short xrf[8192];       // 64 rows A-frag order
    int t = threadIdx.x;
    // stage x rows (slot-ordered like msg)
#pragma unroll
    for (int p = 0; p < 4; p++) {
        int c = t + 256 * p;
        int g = c >> 6;
        int rt = g >> 2, kb = g & 3;
        int q = (c >> 4) & 3, m = c & 15;
        int row = n0 + rt * 16 + m;
        int oct = kb * 4 + q;
        int4 v = make_int4(0, 0, 0, 0);
        if (row < N) v = *(const int4*)(xb + (size_t)row * DIM + oct * 8);
        *(int4*)&xrf[c * 8] = v;
    }
    // stage root fp32 -> bf16: 4096 float4 chunks
#pragma unroll
    for (int p = 0; p < 16; p++) {
        int c = t + 256 * p;
        int k = c >> 5, of = c & 31;
        float4 v = *(const float4*)(rootM + k * DIM + of * 4);
        ushort4 s;
        s.x = f2b(v.x); s.y = f2b(v.y); s.z = f2b(v.z); s.w = f2b(v.w);
        *(ushort4*)&wt[k * 136 + of * 4] = s;
    }
    __syncthreads();

    int w = t >> 6, l = t & 63, n = l & 15, q = l >> 4;
    f32x4 acc[2][4] = {};
#pragma unroll
    for (int kb = 0; kb < 4; kb++) {
        bf16x8 a[4];
#pragma unroll
        for (int rt = 0; rt < 4; rt++) a[rt] = *(const bf16x8*)&xrf[((rt * 4 + kb) * 64 + l) * 8];
        int kbase = kb * 32 + q * 8;
#pragma unroll
        for (int c = 0; c < 2; c++) {
            int ob = (w * 2 + c) * 16 + n;
            bf16x8 b;
#pragma unroll
            for (int j = 0; j < 8; j++) b[j] = u2b(wt[(kbase + j) * 136 + ob]);
#pragma unroll
            for (int rt = 0; rt < 4; rt++)
                acc[c][rt] = __builtin_amdgcn_mfma_f32_16x16x32_bf16(a[rt], b, acc[c][rt], 0, 0, 0);
        }
    }
#pragma unroll
    for (int c = 0; c < 2; c++) {
        int col = (w * 2 + c) * 16 + n;
        float bo = bias[col];
#pragma unroll
        for (int rt = 0; rt < 4; rt++) {
#pragma unroll
            for (int rg = 0; rg < 4; rg++) {
                int row = n0 + rt * 16 + q * 4 + rg;
                if (row < N) {
                    float v = accbuf[(size_t)row * DIM + col] + acc[c][rt][rg] + bo;
                    if (mode) {
                        v = fmaxf(v, 0.f);
                        outb[(size_t)row * DIM + col] = f2b(v);
                    } else {
                        outf[(size_t)row * DIM + col] = v;
                    }
                }
            }
        }
    }
}

extern "C" void kernel_launch(void* const* d_in, const int* in_sizes, int n_in,
                              void* d_out, int out_size, void* d_ws, size_t ws_size,
                              hipStream_t stream) {
    const int N = N_NODES, E = N_EDGES, R = N_REL;

    const int* entity = (const int*)d_in[0];
    const int* eidx   = (const int*)d_in[1];
    const int* src    = eidx;
    const int* dst    = eidx + E;
    const int* etype  = (const int*)d_in[2];
    const float* emb  = (const float*)d_in[3];
    const float* basis1 = (const float*)d_in[4];
    const float* att1   = (const float*)d_in[5];
    const float* w1     = (const float*)d_in[6];
    const float* root1  = (const float*)d_in[7];
    const float* bias1  = (const float*)d_in[8];
    const float* basis2 = (const float*)d_in[9];
    const float* att2   = (const float*)d_in[10];
    const float* w2     = (const float*)d_in[11];
    const float* root2  = (const float*)d_in[12];
    const float* bias2  = (const float*)d_in[13];
    float* out = (float*)d_out;

    size_t off = 0;
    auto alloc = [&](size_t bytes) -> void* {
        void* p = (char*)d_ws + off;
        off += (bytes + 255) & ~(size_t)255;
        return p;
    };
    unsigned short* W  = (unsigned short*)alloc((size_t)R * DIM * DIM * 2);
    unsigned short* xb = (unsigned short*)alloc((size_t)N * DIM * 2);
    unsigned short* hb = (unsigned short*)alloc((size_t)N * DIM * 2);
    float* seg    = (float*)alloc((size_t)N * (2 + DIM) * 4);   // nmax | denom | acc
    unsigned* nmax = (unsigned*)seg;
    float* denom  = seg + N;
    float* acc    = seg + 2 * N;
    float* alpha  = (float*)alloc((size_t)E * 4);
    int* meta     = (int*)alloc((size_t)(R + 1) * 4);   // cnt | nchunks
    int* cnt      = meta;
    int* nchunks  = meta + R;
    int* offs     = (int*)alloc((size_t)(R + 1) * 4);
    int* cursor   = (int*)alloc((size_t)R * 4);
    int* eids     = (int*)alloc((size_t)E * 4);
    int* chunk_r  = (int*)alloc((size_t)MAXCH * 4);
    int* chunk_o  = (int*)alloc((size_t)MAXCH * 4);

    // ---- prep ----
    hipMemsetAsync(meta, 0, (size_t)(R + 1) * 4, stream);
    {
        int total4 = N * DIM / 4;
        gather_kernel<<<(total4 + 255) / 256, 256, 0, stream>>>(
            (const float4*)emb, entity, (ushort4*)xb, total4);
    }
    count_kernel<<<(E + 255) / 256, 256, 0, stream>>>(etype, cnt, E);
    scanr_kernel<<<1, 512, 0, stream>>>(cnt, offs, cursor, chunk_r, chunk_o, nchunks, R, E);
    scatter_kernel<<<(E + 255) / 256, 256, 0, stream>>>(etype, cursor, eids, E);

    // ---- layer 1: xb -> hb (relu, bf16) ----
    hipMemsetAsync(seg, 0, (size_t)N * (2 + DIM) * 4, stream);
    logit_kernel<<<E / 4, 256, 0, stream>>>(xb, w1, src, dst, etype, alpha, nmax, E);
    expden_kernel<<<(E + 255) / 256, 256, 0, stream>>>(alpha, dst, nmax, denom, E);
    wmix_kernel<<<dim3(64, 8), 256, 0, stream>>>(att1, basis1, W, R);
    msg_kernel<<<MAXCH, 256, 0, stream>>>(xb, W, chunk_r, chunk_o, nchunks,
                                          eids, offs, src, dst, alpha, denom, acc);
    root_kernel<<<(N + 63) / 64, 256, 0, stream>>>(xb, root1, bias1, acc, hb, nullptr, 1, N);

    // ---- layer 2: hb -> out (fp32) ----
    hipMemsetAsync(seg, 0, (size_t)N * (2 + DIM) * 4, stream);
    logit_kernel<<<E / 4, 256, 0, stream>>>(hb, w2, src, dst, etype, alpha, nmax, E);
    expden_kernel<<<(E + 255) / 256, 256, 0, stream>>>(alpha, dst, nmax, denom, E);
    wmix_kernel<<<dim3(64, 8), 256, 0, stream>>>(att2, basis2, W, R);
    msg_kernel<<<MAXCH, 256, 0, stream>>>(hb, W, chunk_r, chunk_o, nchunks,
                                          eids, offs, src, dst, alpha, denom, acc);
    root_kernel<<<(N + 63) / 64, 256, 0, stream>>>(hb, root2, bias2, acc, nullptr, out, 0, N);
}